// Round 6
// baseline (395.906 us; speedup 1.0000x reference)
//
#include <hip/hip_runtime.h>

#define N_NODES 40000
#define N_EDGES 640000
#define IN_F 128
#define HID_F 256
#define CLS_F 40

// ---------------- small float4 helpers ----------------

__device__ __forceinline__ float4 f4add(float4 a, float4 b) {
    return make_float4(a.x + b.x, a.y + b.y, a.z + b.z, a.w + b.w);
}
__device__ __forceinline__ float4 f4scale(float4 v, float s) {
    return make_float4(v.x * s, v.y * s, v.z * s, v.w * s);
}

// ---------------- CSR build ----------------

__global__ void k_count(const int* __restrict__ dst, int* __restrict__ counts) {
    int e = blockIdx.x * blockDim.x + threadIdx.x;
    if (e < N_EDGES) atomicAdd(&counts[dst[e]], 1);
}

__global__ void k_scan1(const int* __restrict__ counts, int* __restrict__ bsum) {
    __shared__ int s[256];
    int i = blockIdx.x * 256 + threadIdx.x;
    s[threadIdx.x] = (i < N_NODES) ? counts[i] : 0;
    __syncthreads();
    for (int off = 128; off > 0; off >>= 1) {
        if (threadIdx.x < off) s[threadIdx.x] += s[threadIdx.x + off];
        __syncthreads();
    }
    if (threadIdx.x == 0) bsum[blockIdx.x] = s[0];
}

// parallel exclusive scan of nb (<=256) block sums in one block
__global__ void k_scan2(int* __restrict__ bsum, int nb) {
    __shared__ int s[256];
    int t = threadIdx.x;
    int v = (t < nb) ? bsum[t] : 0;
    s[t] = v;
    __syncthreads();
    for (int off = 1; off < 256; off <<= 1) {
        int x = (t >= off) ? s[t - off] : 0;
        __syncthreads();
        s[t] += x;
        __syncthreads();
    }
    if (t < nb) bsum[t] = s[t] - v;   // exclusive
}

// scan3 + norm fused: writes rowptr/cursor and norm/norm2
__global__ void k_scan3(const int* __restrict__ counts, const int* __restrict__ bsum,
                        int* __restrict__ rowptr, int* __restrict__ cursor,
                        float* __restrict__ norm, float* __restrict__ norm2) {
    __shared__ int s[256];
    int t = threadIdx.x;
    int i = blockIdx.x * 256 + t;
    int v = (i < N_NODES) ? counts[i] : 0;
    s[t] = v;
    __syncthreads();
    for (int off = 1; off < 256; off <<= 1) {
        int x = (t >= off) ? s[t - off] : 0;
        __syncthreads();
        s[t] += x;
        __syncthreads();
    }
    if (i < N_NODES) {
        int excl = s[t] - v + bsum[blockIdx.x];
        rowptr[i] = excl;
        cursor[i] = excl;
        float r = rsqrtf(fmaxf((float)v, 1.0f));
        norm[i] = r;
        norm2[i] = r * r;
    }
}

__global__ void k_fill(const int* __restrict__ src, const int* __restrict__ dst,
                       int* __restrict__ cursor, int* __restrict__ csr_src) {
    int e = blockIdx.x * blockDim.x + threadIdx.x;
    if (e < N_EDGES) {
        int d = dst[e];
        int p = atomicAdd(&cursor[d], 1);
        csr_src[p] = src[e];
    }
}

// ---------------- pre-scale: g0 = features * norm[node] ----------------

__global__ void k_pre(const float* __restrict__ f, const float* __restrict__ norm,
                      float* __restrict__ g0) {
    int i4 = blockIdx.x * 256 + threadIdx.x;
    if (i4 < N_NODES * (IN_F / 4)) {
        int node = i4 >> 5;                 // IN_F/4 = 32 float4 per row
        float4 v = ((const float4*)f)[i4];
        ((float4*)g0)[i4] = f4scale(v, norm[node]);
    }
}

// ---------------- W1 transpose: W1t[j][k] = W1[k][j] ----------------

__global__ void k_w1t(const float* __restrict__ W1, float* __restrict__ W1t) {
    int idx = blockIdx.x * 256 + threadIdx.x;
    if (idx < HID_F * IN_F) {
        int j = idx >> 7, k = idx & 127;    // IN_F = 128
        W1t[idx] = W1[k * HID_F + j];
    }
}

// ---------------- propagation hop (gather, no atomics) ----------------
// out[n][:] = oscale(n) * sum_{s in in-edges(n)} in[s][:]
// 32 lanes per node, float4 per lane. 8 row-gathers in flight per group.

__global__ __launch_bounds__(256) void k_hop(
        const float* __restrict__ gin, float* __restrict__ gout,
        const int* __restrict__ csr_src, const int* __restrict__ rowptr,
        const int* __restrict__ counts, const float* __restrict__ oscale,
        int use_oscale) {
    int gid  = blockIdx.x * 8 + (threadIdx.x >> 5);
    int lane = threadIdx.x & 31;
    if (gid >= N_NODES) return;
    int start = rowptr[gid];
    int cnt   = counts[gid];
    const int* cp = csr_src + start;
    float4 a0 = make_float4(0.f, 0.f, 0.f, 0.f);
    float4 a1 = a0, a2 = a0, a3 = a0;
    int i = 0;
    for (; i + 8 <= cnt; i += 8) {
        int s0 = cp[i+0], s1 = cp[i+1], s2 = cp[i+2], s3 = cp[i+3];
        int s4 = cp[i+4], s5 = cp[i+5], s6 = cp[i+6], s7 = cp[i+7];
        float4 v0 = ((const float4*)(gin + (size_t)s0 * IN_F))[lane];
        float4 v1 = ((const float4*)(gin + (size_t)s1 * IN_F))[lane];
        float4 v2 = ((const float4*)(gin + (size_t)s2 * IN_F))[lane];
        float4 v3 = ((const float4*)(gin + (size_t)s3 * IN_F))[lane];
        float4 v4 = ((const float4*)(gin + (size_t)s4 * IN_F))[lane];
        float4 v5 = ((const float4*)(gin + (size_t)s5 * IN_F))[lane];
        float4 v6 = ((const float4*)(gin + (size_t)s6 * IN_F))[lane];
        float4 v7 = ((const float4*)(gin + (size_t)s7 * IN_F))[lane];
        a0 = f4add(a0, v0);
        a1 = f4add(a1, v1);
        a2 = f4add(a2, v2);
        a3 = f4add(a3, v3);
        a0 = f4add(a0, v4);
        a1 = f4add(a1, v5);
        a2 = f4add(a2, v6);
        a3 = f4add(a3, v7);
    }
    for (; i + 4 <= cnt; i += 4) {
        int s0 = cp[i+0], s1 = cp[i+1], s2 = cp[i+2], s3 = cp[i+3];
        float4 v0 = ((const float4*)(gin + (size_t)s0 * IN_F))[lane];
        float4 v1 = ((const float4*)(gin + (size_t)s1 * IN_F))[lane];
        float4 v2 = ((const float4*)(gin + (size_t)s2 * IN_F))[lane];
        float4 v3 = ((const float4*)(gin + (size_t)s3 * IN_F))[lane];
        a0 = f4add(a0, v0);
        a1 = f4add(a1, v1);
        a2 = f4add(a2, v2);
        a3 = f4add(a3, v3);
    }
    for (; i < cnt; i++) {
        int s = cp[i];
        float4 v = ((const float4*)(gin + (size_t)s * IN_F))[lane];
        a0 = f4add(a0, v);
    }
    float4 r = f4add(f4add(a0, a1), f4add(a2, a3));
    if (use_oscale) r = f4scale(r, oscale[gid]);
    ((float4*)(gout + (size_t)gid * IN_F))[lane] = r;
}

// ---------------- fused MLP (GEMV, scalar-broadcast weights, 8-way k-split) ----
// out[n] = relu((h2[n]*norm[n]) @ W1 + b1) @ W2 + b2
// Block = 512 thr = 8 waves; lane = node (64/block, 625 blocks); wave g = k-octant
// (16 feats, 4 float4 in VGPRs). All weight/bias addresses wave-uniform -> s_load;
// hot loop is v_fmac v,s,v only. 5000 waves (4.9/SIMD), 512thr x 4 blk/CU = 32
// waves/CU: enough residency to hide the s_load (K$-miss ~L2) stalls that capped
// v5 at 23% VALU with 2.44 waves/SIMD.
// Per 16-j tile: wave writes 4 float4 partials to ts4[jj4][g][lane]
// (lane-consecutive b128 = capacity-floor, conflict-free), barrier, every wave
// reduces the 8 octant partials, relu, accumulates its 5-class slice of GEMM2.

__global__ __launch_bounds__(512) void k_mlp(
        const float* __restrict__ h2, const float* __restrict__ norm,
        const float* __restrict__ W1t, const float* __restrict__ b1,
        const float* __restrict__ W2, const float* __restrict__ b2,
        float* __restrict__ out) {
    __shared__ __align__(16) float4 ts4[4][8][64];   // 32 KB
    int t    = threadIdx.x;
    int lane = t & 63;
    int g    = __builtin_amdgcn_readfirstlane(t >> 6);   // 0..7, wave-uniform
    int n    = blockIdx.x * 64 + lane;

    // stage this node's k-octant (16 floats), trailing norm folded in
    float4 h[4];
    const float4* hp = (const float4*)(h2 + (size_t)n * IN_F + g * 16);
    float nr = norm[n];
    #pragma unroll
    for (int i = 0; i < 4; i++) h[i] = f4scale(hp[i], nr);

    const float* wq = W1t + g * 16;        // + j*IN_F, wave-uniform
    float oacc[5];
    #pragma unroll
    for (int c = 0; c < 5; c++) oacc[c] = b2[g * 5 + c];   // uniform s_load

    for (int jt = 0; jt < 16; jt++) {
        __syncthreads();                   // prev tile's reads done before overwrite
        #pragma unroll
        for (int jj4 = 0; jj4 < 4; jj4++) {
            float4 p;
            #pragma unroll
            for (int q = 0; q < 4; q++) {
                int j = jt * 16 + jj4 * 4 + q;
                const float* w = wq + (size_t)j * IN_F;      // uniform -> s_load
                float a0 = 0.f, a1 = 0.f, a2 = 0.f, a3 = 0.f;
                a0 = fmaf(h[0].x, w[0],  a0);
                a0 = fmaf(h[0].y, w[1],  a0);
                a0 = fmaf(h[0].z, w[2],  a0);
                a0 = fmaf(h[0].w, w[3],  a0);
                a1 = fmaf(h[1].x, w[4],  a1);
                a1 = fmaf(h[1].y, w[5],  a1);
                a1 = fmaf(h[1].z, w[6],  a1);
                a1 = fmaf(h[1].w, w[7],  a1);
                a2 = fmaf(h[2].x, w[8],  a2);
                a2 = fmaf(h[2].y, w[9],  a2);
                a2 = fmaf(h[2].z, w[10], a2);
                a2 = fmaf(h[2].w, w[11], a2);
                a3 = fmaf(h[3].x, w[12], a3);
                a3 = fmaf(h[3].y, w[13], a3);
                a3 = fmaf(h[3].z, w[14], a3);
                a3 = fmaf(h[3].w, w[15], a3);
                (&p.x)[q] = (a0 + a1) + (a2 + a3);
            }
            ts4[jj4][g][lane] = p;         // lane-consecutive b128 write
        }
        __syncthreads();
        #pragma unroll
        for (int jj4 = 0; jj4 < 4; jj4++) {
            float4 v = ts4[jj4][0][lane];
            #pragma unroll
            for (int gg = 1; gg < 8; gg++) v = f4add(v, ts4[jj4][gg][lane]);
            int jb = jt * 16 + jj4 * 4;
            v.x = fmaxf(v.x + b1[jb + 0], 0.f);   // b1: uniform s_load
            v.y = fmaxf(v.y + b1[jb + 1], 0.f);
            v.z = fmaxf(v.z + b1[jb + 2], 0.f);
            v.w = fmaxf(v.w + b1[jb + 3], 0.f);
            #pragma unroll
            for (int q = 0; q < 4; q++) {
                float vv = (&v.x)[q];
                const float* w2r = W2 + (size_t)(jb + q) * CLS_F + g * 5;  // uniform
                #pragma unroll
                for (int c = 0; c < 5; c++)
                    oacc[c] = fmaf(vv, w2r[c], oacc[c]);
            }
        }
    }

    float* op = out + (size_t)n * CLS_F + g * 5;
    #pragma unroll
    for (int c = 0; c < 5; c++) op[c] = oacc[c];
}

// ---------------- launch ----------------

extern "C" void kernel_launch(void* const* d_in, const int* in_sizes, int n_in,
                              void* d_out, int out_size, void* d_ws, size_t ws_size,
                              hipStream_t stream) {
    const float* features = (const float*)d_in[0];
    const int*   src      = (const int*)d_in[1];
    const int*   dst      = (const int*)d_in[2];
    const float* W1       = (const float*)d_in[3];
    const float* b1       = (const float*)d_in[4];
    const float* W2       = (const float*)d_in[5];
    const float* b2       = (const float*)d_in[6];
    float*       out      = (float*)d_out;

    char* ws = (char*)d_ws;
    size_t off = 0;
    auto alloc = [&](size_t bytes) -> void* {
        void* p = ws + off;
        off += (bytes + 255) & ~(size_t)255;
        return p;
    };
    int*   counts = (int*)alloc((size_t)N_NODES * 4);
    int*   rowptr = (int*)alloc((size_t)N_NODES * 4);
    int*   cursor = (int*)alloc((size_t)N_NODES * 4);
    int*   bsum   = (int*)alloc(256 * 4);
    float* norm   = (float*)alloc((size_t)N_NODES * 4);
    float* norm2  = (float*)alloc((size_t)N_NODES * 4);
    float* W1t    = (float*)alloc((size_t)HID_F * IN_F * 4);
    int*   csr    = (int*)alloc((size_t)N_EDGES * 4);
    float* bufA   = (float*)alloc((size_t)N_NODES * IN_F * 4);
    float* bufB   = (float*)alloc((size_t)N_NODES * IN_F * 4);

    hipMemsetAsync(counts, 0, (size_t)N_NODES * 4, stream);

    int nb = (N_NODES + 255) / 256;   // 157
    k_count<<<(N_EDGES + 255) / 256, 256, 0, stream>>>(dst, counts);
    k_scan1<<<nb, 256, 0, stream>>>(counts, bsum);
    k_scan2<<<1, 256, 0, stream>>>(bsum, nb);
    k_scan3<<<nb, 256, 0, stream>>>(counts, bsum, rowptr, cursor, norm, norm2);
    k_fill<<<(N_EDGES + 255) / 256, 256, 0, stream>>>(src, dst, cursor, csr);
    k_w1t<<<(HID_F * IN_F + 255) / 256, 256, 0, stream>>>(W1, W1t);

    // g0 = features * norm  -> bufA
    k_pre<<<(N_NODES * (IN_F / 4) + 255) / 256, 256, 0, stream>>>(features, norm, bufA);
    // hop1: bufB = norm2[dst] * sum(g0[src])   (pre-scaled for hop2)
    k_hop<<<(N_NODES + 7) / 8, 256, 0, stream>>>(bufA, bufB, csr, rowptr, counts, norm2, 1);
    // hop2: bufA = sum(bufB[src])              (trailing norm folded into MLP)
    k_hop<<<(N_NODES + 7) / 8, 256, 0, stream>>>(bufB, bufA, csr, rowptr, counts, norm2, 0);

    k_mlp<<<N_NODES / 64, 512, 0, stream>>>(bufA, norm, W1t, b1, W2, b2, out);
}